// Round 1
// baseline (1305.034 us; speedup 1.0000x reference)
//
#include <hip/hip_runtime.h>
#include <stdint.h>

#define G      128
#define H1D    128
#define OUTW   128
#define RNUM   6
#define NB     32

#define FMA4(A, m, w0, w1, w2, w3) do { \
  (A).x += (m).x*(w0).x + (m).y*(w1).x + (m).z*(w2).x + (m).w*(w3).x; \
  (A).y += (m).x*(w0).y + (m).y*(w1).y + (m).z*(w2).y + (m).w*(w3).y; \
  (A).z += (m).x*(w0).z + (m).y*(w1).z + (m).z*(w2).z + (m).w*(w3).z; \
  (A).w += (m).x*(w0).w + (m).y*(w1).w + (m).z*(w2).w + (m).w*(w3).w; } while(0)

// ---------------- K1: degree + per-(relation,dst) counts ----------------
__global__ void count_kernel(const int* __restrict__ ei, const int* __restrict__ et,
                             int* __restrict__ deg, int* __restrict__ cntR,
                             int N, int E) {
    int e = blockIdx.x * blockDim.x + threadIdx.x;
    if (e >= E) return;
    int dst = ei[E + e];
    int r   = et[e];
    atomicAdd(&deg[dst], 1);
    atomicAdd(&cntR[r * N + dst], 1);
}

// ---------------- K2: exclusive scan (single block) ----------------
__global__ __launch_bounds__(1024)
void scan_kernel(const int* __restrict__ deg, int* __restrict__ row_ptr,
                 int* __restrict__ cursor, int n) {
    __shared__ int buf[1024];
    __shared__ int carry_s;
    int tid = threadIdx.x;
    if (tid == 0) carry_s = 0;
    __syncthreads();
    for (int base = 0; base < n; base += 1024) {
        int v = (base + tid < n) ? deg[base + tid] : 0;
        buf[tid] = v;
        __syncthreads();
        int x = v;
        for (int off = 1; off < 1024; off <<= 1) {
            int y = (tid >= off) ? buf[tid - off] : 0;
            __syncthreads();
            x += y;
            buf[tid] = x;
            __syncthreads();
        }
        int carry = carry_s;
        if (base + tid < n) {
            int excl = carry + x - v;
            row_ptr[base + tid] = excl;
            cursor[base + tid]  = excl;
        }
        __syncthreads();
        if (tid == 1023) carry_s = carry + x;
        __syncthreads();
    }
    if (tid == 0) row_ptr[n] = carry_s;
}

// ---------------- K3: scatter edges into CSR (src | rel<<16 packed) ----------------
__global__ void scatter_kernel(const int* __restrict__ ei, const int* __restrict__ et,
                               int* __restrict__ cursor, unsigned int* __restrict__ epack,
                               int N, int E) {
    int e = blockIdx.x * blockDim.x + threadIdx.x;
    if (e >= E) return;
    int src = ei[e];
    int dst = ei[E + e];
    int r   = et[e];
    int pos = atomicAdd(&cursor[dst], 1);
    epack[pos] = (unsigned int)src | ((unsigned int)r << 16);
}

// ---------------- K4: fused RGCN (aggregate means -> GEMM) ----------------
// 512 threads, 32 nodes/block. LDS panel M[32][896] = [6 relation means | own x].
__global__ __launch_bounds__(512)
void rgcn_kernel(const float* __restrict__ x, const float* __restrict__ Wrel,
                 const float* __restrict__ Wroot, const float* __restrict__ brgcn,
                 const int* __restrict__ rowptr, const unsigned int* __restrict__ epack,
                 const int* __restrict__ cntR, float* __restrict__ xout, int N) {
    extern __shared__ float Mld[];   // NB * 896 floats
    const int tid  = threadIdx.x;
    const int wave = tid >> 6;
    const int l    = tid & 63;
    const int nodeBase = blockIdx.x * NB;

    // -------- aggregation: each wave owns 4 nodes; lane l holds features 2l,2l+1 --------
    for (int j = 0; j < 4; ++j) {
        const int s = wave + 8 * j;        // block-node slot
        const int i = nodeBase + s;
        float2 a0 = {0.f,0.f}, a1 = {0.f,0.f}, a2 = {0.f,0.f};
        float2 a3 = {0.f,0.f}, a4 = {0.f,0.f}, a5 = {0.f,0.f};
        if (i < N) {
            int e   = rowptr[i];
            int end = rowptr[i + 1];
#define ACCR(RV, V) { int r_ = __builtin_amdgcn_readfirstlane((int)(RV)); \
    if      (r_ == 0) { a0.x += (V).x; a0.y += (V).y; } \
    else if (r_ == 1) { a1.x += (V).x; a1.y += (V).y; } \
    else if (r_ == 2) { a2.x += (V).x; a2.y += (V).y; } \
    else if (r_ == 3) { a3.x += (V).x; a3.y += (V).y; } \
    else if (r_ == 4) { a4.x += (V).x; a4.y += (V).y; } \
    else              { a5.x += (V).x; a5.y += (V).y; } }
            while (e + 4 <= end) {
                unsigned p0 = epack[e+0], p1 = epack[e+1], p2 = epack[e+2], p3 = epack[e+3];
                float2 x0 = *(const float2*)(x + (size_t)(p0 & 0xFFFFu) * G + 2*l);
                float2 x1 = *(const float2*)(x + (size_t)(p1 & 0xFFFFu) * G + 2*l);
                float2 x2 = *(const float2*)(x + (size_t)(p2 & 0xFFFFu) * G + 2*l);
                float2 x3 = *(const float2*)(x + (size_t)(p3 & 0xFFFFu) * G + 2*l);
                ACCR(p0 >> 16, x0); ACCR(p1 >> 16, x1);
                ACCR(p2 >> 16, x2); ACCR(p3 >> 16, x3);
                e += 4;
            }
            while (e < end) {
                unsigned p0 = epack[e];
                float2 x0 = *(const float2*)(x + (size_t)(p0 & 0xFFFFu) * G + 2*l);
                ACCR(p0 >> 16, x0);
                ++e;
            }
#undef ACCR
        }
        // scale by 1/max(cnt,1) and write LDS panel
        float* Mrow = Mld + (size_t)s * 896;
#define WR(RIDX, A) { \
    float c_  = (i < N) ? (float)cntR[(RIDX) * N + i] : 1.f; \
    float sc_ = 1.f / fmaxf(c_, 1.f); \
    float2 t_; t_.x = (A).x * sc_; t_.y = (A).y * sc_; \
    *(float2*)(Mrow + (RIDX) * G + 2*l) = t_; }
        WR(0, a0); WR(1, a1); WR(2, a2); WR(3, a3); WR(4, a4); WR(5, a5);
#undef WR
        float2 xo = {0.f, 0.f};
        if (i < N) xo = *(const float2*)(x + (size_t)i * G + 2*l);
        *(float2*)(Mrow + 768 + 2*l) = xo;
    }
    __syncthreads();

    // -------- GEMM: 32x896 (LDS) @ 896x128 (L1/L2) -> 32x128 --------
    const int cg = tid & 31;        // 32 col groups * 4 cols
    const int ng = tid >> 5;        // 16 node groups * 2 nodes
    const int c0 = cg * 4;
    const int n0 = ng * 2;
    const float4 bb = *(const float4*)(brgcn + c0);
    float4 acc0 = bb, acc1 = bb;
    const float* M0 = Mld + (size_t)n0 * 896;
    const float* M1 = Mld + (size_t)(n0 + 1) * 896;

    for (int d = 0; d < 768; d += 4) {
        const float* Wp = Wrel + (size_t)d * OUTW + c0;
        float4 w0 = *(const float4*)(Wp);
        float4 w1 = *(const float4*)(Wp + 128);
        float4 w2 = *(const float4*)(Wp + 256);
        float4 w3 = *(const float4*)(Wp + 384);
        float4 m0 = *(const float4*)(M0 + d);
        float4 m1 = *(const float4*)(M1 + d);
        FMA4(acc0, m0, w0, w1, w2, w3);
        FMA4(acc1, m1, w0, w1, w2, w3);
    }
    for (int d = 0; d < 128; d += 4) {
        const float* Wp = Wroot + (size_t)d * OUTW + c0;
        float4 w0 = *(const float4*)(Wp);
        float4 w1 = *(const float4*)(Wp + 128);
        float4 w2 = *(const float4*)(Wp + 256);
        float4 w3 = *(const float4*)(Wp + 384);
        float4 m0 = *(const float4*)(M0 + 768 + d);
        float4 m1 = *(const float4*)(M1 + 768 + d);
        FMA4(acc0, m0, w0, w1, w2, w3);
        FMA4(acc1, m1, w0, w1, w2, w3);
    }
    const int i0 = nodeBase + n0;
    const int i1 = i0 + 1;
    if (i0 < N) *(float4*)(xout + (size_t)i0 * OUTW + c0) = acc0;
    if (i1 < N) *(float4*)(xout + (size_t)i1 * OUTW + c0) = acc1;
}

// ---------------- K5: q|k|v|skip projections ----------------
// grid (tiles, 4); block 512. Each block: 64 nodes x one 128-col quadrant.
__global__ __launch_bounds__(512)
void qkvs_kernel(const float* __restrict__ xr,
                 const float* __restrict__ Wq, const float* __restrict__ bq,
                 const float* __restrict__ Wk, const float* __restrict__ bk,
                 const float* __restrict__ Wv, const float* __restrict__ bv,
                 const float* __restrict__ Ws, const float* __restrict__ bs,
                 float* __restrict__ qkvs, int N) {
    __shared__ float X[64][128];
    const int tid  = threadIdx.x;
    const int base = blockIdx.x * 64;
    const int quad = blockIdx.y;

    for (int p = 0; p < 4; ++p) {
        int flat4 = p * 512 + tid;
        int row  = flat4 >> 5;
        int col4 = (flat4 & 31) * 4;
        float4 v = {0.f, 0.f, 0.f, 0.f};
        if (base + row < N) v = *(const float4*)(xr + (size_t)(base + row) * H1D + col4);
        *(float4*)(&X[row][col4]) = v;
    }
    __syncthreads();

    const float* W = (quad == 0) ? Wq : (quad == 1) ? Wk : (quad == 2) ? Wv : Ws;
    const float* b = (quad == 0) ? bq : (quad == 1) ? bk : (quad == 2) ? bv : bs;

    const int cg = tid & 31, ng = tid >> 5;   // 16 node groups * 4 nodes
    const int c0 = cg * 4;
    const float4 bb = *(const float4*)(b + c0);
    float4 acc0 = bb, acc1 = bb, acc2 = bb, acc3 = bb;

    for (int d = 0; d < 128; d += 4) {
        const float* Wp = W + (size_t)d * OUTW + c0;
        float4 w0 = *(const float4*)(Wp);
        float4 w1 = *(const float4*)(Wp + 128);
        float4 w2 = *(const float4*)(Wp + 256);
        float4 w3 = *(const float4*)(Wp + 384);
        float4 m0 = *(const float4*)(&X[ng * 4 + 0][d]);
        float4 m1 = *(const float4*)(&X[ng * 4 + 1][d]);
        float4 m2 = *(const float4*)(&X[ng * 4 + 2][d]);
        float4 m3 = *(const float4*)(&X[ng * 4 + 3][d]);
        FMA4(acc0, m0, w0, w1, w2, w3);
        FMA4(acc1, m1, w0, w1, w2, w3);
        FMA4(acc2, m2, w0, w1, w2, w3);
        FMA4(acc3, m3, w0, w1, w2, w3);
    }
#define STORE(J, A) { int i_ = base + ng * 4 + (J); \
    if (i_ < N) *(float4*)(qkvs + (size_t)i_ * 512 + quad * 128 + c0) = A; }
    STORE(0, acc0); STORE(1, acc1); STORE(2, acc2); STORE(3, acc3);
#undef STORE
}

// ---------------- K6: attention (online softmax, wave per node) + BN partials ----------------
__global__ __launch_bounds__(256)
void attn_kernel(const float* __restrict__ qkvs, const int* __restrict__ rowptr,
                 const unsigned int* __restrict__ epack, float* __restrict__ out,
                 float* __restrict__ bnS, float* __restrict__ bnQ, int N) {
    __shared__ float sS[128];
    __shared__ float sQ[128];
    const int tid = threadIdx.x;
    if (tid < 128) { sS[tid] = 0.f; sQ[tid] = 0.f; }
    __syncthreads();

    const int wave = tid >> 6;
    const int l    = tid & 63;
    const int stride = gridDim.x * 4;
    const float QS = 0.17677669529663687f;  // 1/sqrt(32)

    float2 bsum = {0.f, 0.f}, bsq = {0.f, 0.f};

    for (int i = blockIdx.x * 4 + wave; i < N; i += stride) {
        float2 q2 = *(const float2*)(qkvs + (size_t)i * 512 + 2*l);
        q2.x *= QS; q2.y *= QS;
        float m = -INFINITY, den = 0.f;
        float2 acc = {0.f, 0.f};
        int e   = rowptr[i];
        int end = rowptr[i + 1];
        for (; e < end; ++e) {
            unsigned p = epack[e];
            const float* srcp = qkvs + (size_t)(p & 0xFFFFu) * 512;
            float2 k2 = *(const float2*)(srcp + 128 + 2*l);
            float2 v2 = *(const float2*)(srcp + 256 + 2*l);
            float part = q2.x * k2.x + q2.y * k2.y;
            part += __shfl_xor(part, 1, 16);
            part += __shfl_xor(part, 2, 16);
            part += __shfl_xor(part, 4, 16);
            part += __shfl_xor(part, 8, 16);       // head score, uniform in 16-lane group
            float mn = fmaxf(m, part);
            float rs = __expf(m - mn);             // first edge: exp(-inf)=0, safe
            float pe = __expf(part - mn);
            den   = den * rs + pe;
            acc.x = acc.x * rs + pe * v2.x;
            acc.y = acc.y * rs + pe * v2.y;
            m = mn;
        }
        float inv = 1.f / (den + 1e-16f);
        float2 sk = *(const float2*)(qkvs + (size_t)i * 512 + 384 + 2*l);
        float2 o;
        o.x = acc.x * inv + sk.x;
        o.y = acc.y * inv + sk.y;
        *(float2*)(out + (size_t)i * OUTW + 2*l) = o;
        bsum.x += o.x; bsum.y += o.y;
        bsq.x  += o.x * o.x; bsq.y += o.y * o.y;
    }

    atomicAdd(&sS[2*l],     bsum.x);
    atomicAdd(&sS[2*l + 1], bsum.y);
    atomicAdd(&sQ[2*l],     bsq.x);
    atomicAdd(&sQ[2*l + 1], bsq.y);
    __syncthreads();
    if (tid < 128) {
        atomicAdd(&bnS[tid], sS[tid]);
        atomicAdd(&bnQ[tid], sQ[tid]);
    }
}

// ---------------- K7: BN stats -> per-column affine A,B ----------------
__global__ void bnstats_kernel(const float* __restrict__ bnS, const float* __restrict__ bnQ,
                               const float* __restrict__ gamma, const float* __restrict__ beta,
                               float* __restrict__ bnA, float* __restrict__ bnB, int N) {
    int c = threadIdx.x;
    if (c >= 128) return;
    float fN  = (float)N;
    float mu  = bnS[c] / fN;
    float var = bnQ[c] / fN - mu * mu;
    float rv  = rsqrtf(var + 1e-5f);
    float A   = rv * gamma[c];
    bnA[c] = A;
    bnB[c] = beta[c] - mu * A;
}

// ---------------- K8: BN apply + LeakyReLU (in-place on d_out) ----------------
__global__ void apply_kernel(float* __restrict__ out, const float* __restrict__ bnA,
                             const float* __restrict__ bnB, int total4) {
    int idx4 = blockIdx.x * blockDim.x + threadIdx.x;
    if (idx4 >= total4) return;
    float4 v = ((const float4*)out)[idx4];
    int c0 = (idx4 * 4) & 127;
    float y;
    y = bnA[c0    ] * v.x + bnB[c0    ]; v.x = (y > 0.f) ? y : 0.01f * y;
    y = bnA[c0 + 1] * v.y + bnB[c0 + 1]; v.y = (y > 0.f) ? y : 0.01f * y;
    y = bnA[c0 + 2] * v.z + bnB[c0 + 2]; v.z = (y > 0.f) ? y : 0.01f * y;
    y = bnA[c0 + 3] * v.w + bnB[c0 + 3]; v.w = (y > 0.f) ? y : 0.01f * y;
    ((float4*)out)[idx4] = v;
}

// ---------------- launch ----------------
extern "C" void kernel_launch(void* const* d_in, const int* in_sizes, int n_in,
                              void* d_out, int out_size, void* d_ws, size_t ws_size,
                              hipStream_t stream) {
    const float* x     = (const float*)d_in[0];
    const int*   ei    = (const int*)  d_in[2];
    const int*   et    = (const int*)  d_in[3];
    const float* Wrel  = (const float*)d_in[4];
    const float* Wroot = (const float*)d_in[5];
    const float* brg   = (const float*)d_in[6];
    const float* Wq    = (const float*)d_in[7];
    const float* bq    = (const float*)d_in[8];
    const float* Wk    = (const float*)d_in[9];
    const float* bk    = (const float*)d_in[10];
    const float* Wv    = (const float*)d_in[11];
    const float* bv    = (const float*)d_in[12];
    const float* Wsk   = (const float*)d_in[13];
    const float* bsk   = (const float*)d_in[14];
    const float* gamma = (const float*)d_in[15];
    const float* beta  = (const float*)d_in[16];
    float* out = (float*)d_out;

    const int N = in_sizes[0] / G;
    const int E = in_sizes[3];

    // workspace carve (zero-zone first: deg, cntR, bn accumulators)
    char* w = (char*)d_ws;
    int* deg   = (int*)w;            w += (size_t)N * 4;
    int* cntR  = (int*)w;            w += (size_t)RNUM * N * 4;
    float* bnS = (float*)w;          w += 128 * 4;
    float* bnQ = (float*)w;          w += 128 * 4;
    float* bnA = (float*)w;          w += 128 * 4;
    float* bnB = (float*)w;          w += 128 * 4;
    size_t zero_bytes = (size_t)(w - (char*)d_ws);
    int* rowptr = (int*)w;           w += (size_t)(N + 1) * 4;
    int* cursor = (int*)w;           w += (size_t)N * 4;
    unsigned int* epack = (unsigned int*)w; w += (size_t)E * 4;
    w = (char*)(((uintptr_t)w + 255) & ~(uintptr_t)255);
    float* xr   = (float*)w;         w += (size_t)N * H1D * 4;
    w = (char*)(((uintptr_t)w + 255) & ~(uintptr_t)255);
    float* qkvs = (float*)w;         w += (size_t)N * 512 * 4;

    hipMemsetAsync(d_ws, 0, zero_bytes, stream);

    int eb = (E + 255) / 256;
    count_kernel<<<eb, 256, 0, stream>>>(ei, et, deg, cntR, N, E);
    scan_kernel<<<1, 1024, 0, stream>>>(deg, rowptr, cursor, N);
    scatter_kernel<<<eb, 256, 0, stream>>>(ei, et, cursor, epack, N, E);

    int rgcn_blocks = (N + NB - 1) / NB;
    size_t rgcn_lds = (size_t)NB * 896 * sizeof(float);
    rgcn_kernel<<<rgcn_blocks, 512, rgcn_lds, stream>>>(x, Wrel, Wroot, brg,
                                                        rowptr, epack, cntR, xr, N);

    dim3 g5((N + 63) / 64, 4);
    qkvs_kernel<<<g5, 512, 0, stream>>>(xr, Wq, bq, Wk, bk, Wv, bv, Wsk, bsk, qkvs, N);

    attn_kernel<<<2048, 256, 0, stream>>>(qkvs, rowptr, epack, out, bnS, bnQ, N);

    bnstats_kernel<<<1, 128, 0, stream>>>(bnS, bnQ, gamma, beta, bnA, bnB, N);

    int total4 = N * OUTW / 4;
    apply_kernel<<<(total4 + 255) / 256, 256, 0, stream>>>(out, bnA, bnB, total4);
}

// Round 2
// 970.179 us; speedup vs baseline: 1.3451x; 1.3451x over previous
//
#include <hip/hip_runtime.h>
#include <hip/hip_fp16.h>
#include <stdint.h>

#define G      128
#define OUTW   128
#define RNUM   6

typedef unsigned short us;

__device__ inline float h2f(us u) { __half h; *(us*)&h = u; return __half2float(h); }
__device__ inline us f2h(float f) { __half h = __float2half(f); return *(us*)&h; }

#define FMA4(A, m, w0, w1, w2, w3) do { \
  (A).x += (m).x*(w0).x + (m).y*(w1).x + (m).z*(w2).x + (m).w*(w3).x; \
  (A).y += (m).x*(w0).y + (m).y*(w1).y + (m).z*(w2).y + (m).w*(w3).y; \
  (A).z += (m).x*(w0).z + (m).y*(w1).z + (m).z*(w2).z + (m).w*(w3).z; \
  (A).w += (m).x*(w0).w + (m).y*(w1).w + (m).z*(w2).w + (m).w*(w3).w; } while(0)

// ---------------- K1: degree + per-(relation,dst) counts ----------------
__global__ void count_kernel(const int* __restrict__ ei, const int* __restrict__ et,
                             int* __restrict__ deg, int* __restrict__ cntR,
                             int N, int E) {
    int e = blockIdx.x * blockDim.x + threadIdx.x;
    if (e >= E) return;
    int dst = ei[E + e];
    int r   = et[e];
    atomicAdd(&deg[dst], 1);
    atomicAdd(&cntR[r * N + dst], 1);
}

// ---------------- scan: 3-phase ----------------
__global__ __launch_bounds__(256)
void scan_part(const int* __restrict__ deg, int* __restrict__ bsum, int n) {
    __shared__ int s[256];
    int base = blockIdx.x * 1024, t = threadIdx.x;
    int v = 0;
    for (int j = 0; j < 4; ++j) { int idx = base + j * 256 + t; if (idx < n) v += deg[idx]; }
    s[t] = v; __syncthreads();
    for (int off = 128; off; off >>= 1) { if (t < off) s[t] += s[t + off]; __syncthreads(); }
    if (!t) bsum[blockIdx.x] = s[0];
}

__global__ void scan_top(const int* __restrict__ bsum, int* __restrict__ boff,
                         int* __restrict__ rowptr, int nb, int n) {
    int t = threadIdx.x;              // 64 threads, nb <= 64
    int v = (t < nb) ? bsum[t] : 0;
    for (int off = 1; off < 64; off <<= 1) {
        int y = __shfl_up(v, off);
        if (t >= off) v += y;
    }
    if (t < nb) boff[t + 1] = v;
    if (!t) boff[0] = 0;
    if (t == 63) rowptr[n] = v;       // grand total
}

__global__ __launch_bounds__(256)
void scan_apply(const int* __restrict__ deg, const int* __restrict__ boff,
                int* __restrict__ rowptr, int* __restrict__ cursor, int n) {
    __shared__ int L[1024];
    __shared__ int SS[256];
    int base = blockIdx.x * 1024, t = threadIdx.x;
    for (int j = 0; j < 4; ++j) { int idx = base + j * 256 + t; L[j * 256 + t] = (idx < n) ? deg[idx] : 0; }
    __syncthreads();
    int s0 = L[t*4] + L[t*4+1] + L[t*4+2] + L[t*4+3];
    SS[t] = s0; __syncthreads();
    for (int off = 1; off < 256; off <<= 1) {
        int y = (t >= off) ? SS[t - off] : 0;
        __syncthreads();
        SS[t] += y;
        __syncthreads();
    }
    int e0 = (t ? SS[t - 1] : 0) + boff[blockIdx.x];
    int4 ov;
    int a;
    a = L[t*4+0]; ov.x = e0; e0 += a;
    a = L[t*4+1]; ov.y = e0; e0 += a;
    a = L[t*4+2]; ov.z = e0; e0 += a;
    a = L[t*4+3]; ov.w = e0; e0 += a;
    int idx0 = base + t * 4;
    if (idx0 + 3 < n) {
        *(int4*)(rowptr + idx0) = ov;
        *(int4*)(cursor + idx0) = ov;
    } else {
        int vals[4] = {ov.x, ov.y, ov.z, ov.w};
        for (int k = 0; k < 4; ++k)
            if (idx0 + k < n) { rowptr[idx0 + k] = vals[k]; cursor[idx0 + k] = vals[k]; }
    }
}

// ---------------- K3: scatter edges into CSR (src | rel<<16 packed) ----------------
__global__ void scatter_kernel(const int* __restrict__ ei, const int* __restrict__ et,
                               int* __restrict__ cursor, unsigned int* __restrict__ epack,
                               int N, int E) {
    int e = blockIdx.x * blockDim.x + threadIdx.x;
    if (e >= E) return;
    int src = ei[e];
    int dst = ei[E + e];
    int r   = et[e];
    int pos = atomicAdd(&cursor[dst], 1);
    epack[pos] = (unsigned int)src | ((unsigned int)r << 16);
}

// ---------------- K: fp32 -> fp16 copy of x ----------------
__global__ void xhalf_kernel(const float* __restrict__ x, us* __restrict__ xh, int total8) {
    int i = blockIdx.x * blockDim.x + threadIdx.x;
    if (i >= total8) return;
    float4 a = ((const float4*)x)[2*i];
    float4 b = ((const float4*)x)[2*i+1];
    ushort4 u0 = { f2h(a.x), f2h(a.y), f2h(a.z), f2h(a.w) };
    ushort4 u1 = { f2h(b.x), f2h(b.y), f2h(b.z), f2h(b.w) };
    ((ushort4*)xh)[2*i]   = u0;
    ((ushort4*)xh)[2*i+1] = u1;
}

// ---------------- K4: aggregation (wave per node, no LDS, fp16 gather) ----------------
__global__ __launch_bounds__(256)
void agg_kernel(const us* __restrict__ xh, const int* __restrict__ rowptr,
                const unsigned* __restrict__ epack, const int* __restrict__ cntR,
                us* __restrict__ meanh, int N) {
    const int wv = threadIdx.x >> 6, l = threadIdx.x & 63;
    const int i = blockIdx.x * 4 + wv;
    if (i >= N) return;
    const int e0 = rowptr[i], e1 = rowptr[i + 1];
    float2 a0{0,0}, a1{0,0}, a2{0,0}, a3{0,0}, a4{0,0}, a5{0,0};

#define LOADX(P) (*(const ushort2*)(xh + (size_t)((P) & 0xFFFFu) * G + 2*l))
#define ACC(P, U) { unsigned r_ = (P) >> 16; float vx_ = h2f((U).x), vy_ = h2f((U).y); \
    if      (r_ == 0) { a0.x += vx_; a0.y += vy_; } \
    else if (r_ == 1) { a1.x += vx_; a1.y += vy_; } \
    else if (r_ == 2) { a2.x += vx_; a2.y += vy_; } \
    else if (r_ == 3) { a3.x += vx_; a3.y += vy_; } \
    else if (r_ == 4) { a4.x += vx_; a4.y += vy_; } \
    else              { a5.x += vx_; a5.y += vy_; } }

    for (int base = e0; base < e1; base += 64) {
        const int nc = min(64, e1 - base);
        unsigned pv = 0;
        if (base + l < e1) pv = epack[base + l];
        int j = 0;
        for (; j + 8 <= nc; j += 8) {
            unsigned q0 = (unsigned)__shfl((int)pv, j+0);
            unsigned q1 = (unsigned)__shfl((int)pv, j+1);
            unsigned q2 = (unsigned)__shfl((int)pv, j+2);
            unsigned q3 = (unsigned)__shfl((int)pv, j+3);
            unsigned q4 = (unsigned)__shfl((int)pv, j+4);
            unsigned q5 = (unsigned)__shfl((int)pv, j+5);
            unsigned q6 = (unsigned)__shfl((int)pv, j+6);
            unsigned q7 = (unsigned)__shfl((int)pv, j+7);
            ushort2 u0 = LOADX(q0), u1 = LOADX(q1), u2 = LOADX(q2), u3 = LOADX(q3);
            ushort2 u4 = LOADX(q4), u5 = LOADX(q5), u6 = LOADX(q6), u7 = LOADX(q7);
            ACC(q0,u0); ACC(q1,u1); ACC(q2,u2); ACC(q3,u3);
            ACC(q4,u4); ACC(q5,u5); ACC(q6,u6); ACC(q7,u7);
        }
        for (; j < nc; ++j) {
            unsigned q0 = (unsigned)__shfl((int)pv, j);
            ushort2 u0 = LOADX(q0);
            ACC(q0,u0);
        }
    }
#undef ACC
#undef LOADX

    us* mrow = meanh + (size_t)i * 768 + 2*l;
#define WR(RIDX, A) { \
    float c_ = (float)cntR[(RIDX) * N + i]; \
    float s_ = 1.f / fmaxf(c_, 1.f); \
    ushort2 t_ = { f2h((A).x * s_), f2h((A).y * s_) }; \
    *(ushort2*)(mrow + (RIDX) * G) = t_; }
    WR(0, a0); WR(1, a1); WR(2, a2); WR(3, a3); WR(4, a4); WR(5, a5);
#undef WR
}

// ---------------- K5: RGCN GEMM  xr = [means | x] @ [Wrel; Wroot] + b ----------------
__global__ __launch_bounds__(256)
void rgcn_gemm(const us* __restrict__ meanh, const float* __restrict__ x,
               const float* __restrict__ Wrel, const float* __restrict__ Wroot,
               const float* __restrict__ brg, float* __restrict__ xr, int N) {
    __shared__ float A[64][128];
    const int tid  = threadIdx.x;
    const int base = blockIdx.x * 64;
    const int cg = tid & 31, ng = tid >> 5;
    const int c0 = cg * 4;
    const float4 bb = *(const float4*)(brg + c0);
    float4 acc[8];
#pragma unroll
    for (int r = 0; r < 8; ++r) acc[r] = bb;

    for (int ch = 0; ch < 7; ++ch) {
        // ---- stage A-tile chunk into LDS ----
        if (ch < 6) {
            for (int p = 0; p < 4; ++p) {
                int flat = p * 2048 + tid * 8;       // 8 halves per thread
                int row = flat >> 7, col = flat & 127;
                int gi = base + row;
                float4 lo = {0,0,0,0}, hi = {0,0,0,0};
                if (gi < N) {
                    int4 u = *(const int4*)(meanh + (size_t)gi * 768 + ch * G + col);
                    float2 f0 = __half22float2(*(__half2*)&u.x);
                    float2 f1 = __half22float2(*(__half2*)&u.y);
                    float2 f2 = __half22float2(*(__half2*)&u.z);
                    float2 f3 = __half22float2(*(__half2*)&u.w);
                    lo = {f0.x, f0.y, f1.x, f1.y};
                    hi = {f2.x, f2.y, f3.x, f3.y};
                }
                *(float4*)(&A[row][col])     = lo;
                *(float4*)(&A[row][col + 4]) = hi;
            }
        } else {
            for (int p = 0; p < 8; ++p) {
                int flat4 = p * 1024 + tid * 4;
                int row = flat4 >> 7, col = flat4 & 127;
                int gi = base + row;
                float4 v = {0,0,0,0};
                if (gi < N) v = *(const float4*)(x + (size_t)gi * G + col);
                *(float4*)(&A[row][col]) = v;
            }
        }
        __syncthreads();

        const float* Wb = (ch < 6) ? (Wrel + (size_t)ch * G * OUTW) : Wroot;
        for (int d = 0; d < 128; d += 4) {
            const float* Wp = Wb + (size_t)d * OUTW + c0;
            float4 w0 = *(const float4*)(Wp);
            float4 w1 = *(const float4*)(Wp + 128);
            float4 w2 = *(const float4*)(Wp + 256);
            float4 w3 = *(const float4*)(Wp + 384);
#pragma unroll
            for (int r = 0; r < 8; ++r) {
                float4 m = *(const float4*)(&A[ng * 8 + r][d]);
                FMA4(acc[r], m, w0, w1, w2, w3);
            }
        }
        __syncthreads();
    }
#pragma unroll
    for (int r = 0; r < 8; ++r) {
        int gi = base + ng * 8 + r;
        if (gi < N) *(float4*)(xr + (size_t)gi * OUTW + c0) = acc[r];
    }
}

// ---------------- K6: q|k|v|skip projections ----------------
// qs: [N][256] fp32 = q | skip ; kvh: [N][256] fp16 interleaved {k2l,k2l+1,v2l,v2l+1}
__global__ __launch_bounds__(256)
void qkvs_kernel(const float* __restrict__ xr,
                 const float* __restrict__ Wq, const float* __restrict__ bq,
                 const float* __restrict__ Wk, const float* __restrict__ bk,
                 const float* __restrict__ Wv, const float* __restrict__ bv,
                 const float* __restrict__ Ws, const float* __restrict__ bs,
                 float* __restrict__ qs, us* __restrict__ kvh, int N) {
    __shared__ float A[64][128];
    const int tid  = threadIdx.x;
    const int base = blockIdx.x * 64;
    const int cg = tid & 31, ng = tid >> 5;
    const int c0 = cg * 4;

    for (int p = 0; p < 8; ++p) {
        int flat4 = p * 1024 + tid * 4;
        int row = flat4 >> 7, col = flat4 & 127;
        int gi = base + row;
        float4 v = {0,0,0,0};
        if (gi < N) v = *(const float4*)(xr + (size_t)gi * OUTW + col);
        *(float4*)(&A[row][col]) = v;
    }
    __syncthreads();

    for (int quad = 0; quad < 4; ++quad) {
        const float* W; const float* b;
        switch (quad) {
            case 0: W = Wq; b = bq; break;
            case 1: W = Wk; b = bk; break;
            case 2: W = Wv; b = bv; break;
            default: W = Ws; b = bs; break;
        }
        const float4 bb = *(const float4*)(b + c0);
        float4 acc[8];
#pragma unroll
        for (int r = 0; r < 8; ++r) acc[r] = bb;

        for (int d = 0; d < 128; d += 4) {
            const float* Wp = W + (size_t)d * OUTW + c0;
            float4 w0 = *(const float4*)(Wp);
            float4 w1 = *(const float4*)(Wp + 128);
            float4 w2 = *(const float4*)(Wp + 256);
            float4 w3 = *(const float4*)(Wp + 384);
#pragma unroll
            for (int r = 0; r < 8; ++r) {
                float4 m = *(const float4*)(&A[ng * 8 + r][d]);
                FMA4(acc[r], m, w0, w1, w2, w3);
            }
        }
#pragma unroll
        for (int r = 0; r < 8; ++r) {
            int gi = base + ng * 8 + r;
            if (gi >= N) continue;
            if (quad == 0) {
                *(float4*)(qs + (size_t)gi * 256 + c0) = acc[r];
            } else if (quad == 3) {
                *(float4*)(qs + (size_t)gi * 256 + 128 + c0) = acc[r];
            } else if (quad == 1) {
                us* kp = kvh + (size_t)gi * 256 + (c0 >> 1) * 4;
                ushort2 t0 = { f2h(acc[r].x), f2h(acc[r].y) };
                ushort2 t1 = { f2h(acc[r].z), f2h(acc[r].w) };
                *(ushort2*)(kp)     = t0;
                *(ushort2*)(kp + 4) = t1;
            } else {
                us* vp = kvh + (size_t)gi * 256 + (c0 >> 1) * 4 + 2;
                ushort2 t0 = { f2h(acc[r].x), f2h(acc[r].y) };
                ushort2 t1 = { f2h(acc[r].z), f2h(acc[r].w) };
                *(ushort2*)(vp)     = t0;
                *(ushort2*)(vp + 4) = t1;
            }
        }
    }
}

// ---------------- K7: attention (wave per node, 4-edge batched online softmax) ----------------
__global__ __launch_bounds__(256)
void attn_kernel(const float* __restrict__ qs, const us* __restrict__ kvh,
                 const int* __restrict__ rowptr, const unsigned* __restrict__ epack,
                 float* __restrict__ out, int N) {
    const int wv = threadIdx.x >> 6, l = threadIdx.x & 63;
    const int i = blockIdx.x * 4 + wv;
    if (i >= N) return;
    const float QS = 0.17677669529663687f;   // 1/sqrt(32)

    float2 q2 = *(const float2*)(qs + (size_t)i * 256 + 2*l);
    q2.x *= QS; q2.y *= QS;

    float m = -INFINITY, den = 0.f;
    float2 acc = {0.f, 0.f};
    const int e0 = rowptr[i], e1 = rowptr[i + 1];

#define KVLOAD(P) (*(const ushort4*)(kvh + (size_t)((P) & 0xFFFFu) * 256 + 4*l))
#define SCORE(U, S) { \
    float s_ = q2.x * h2f((U).x) + q2.y * h2f((U).y); \
    s_ += __shfl_xor(s_, 1, 16); s_ += __shfl_xor(s_, 2, 16); \
    s_ += __shfl_xor(s_, 4, 16); s_ += __shfl_xor(s_, 8, 16); \
    S = s_; }

    for (int base = e0; base < e1; base += 64) {
        const int nc = min(64, e1 - base);
        unsigned pv = 0;
        if (base + l < e1) pv = epack[base + l];
        int j = 0;
        for (; j + 4 <= nc; j += 4) {
            unsigned p0 = (unsigned)__shfl((int)pv, j+0);
            unsigned p1 = (unsigned)__shfl((int)pv, j+1);
            unsigned p2 = (unsigned)__shfl((int)pv, j+2);
            unsigned p3 = (unsigned)__shfl((int)pv, j+3);
            ushort4 k0 = KVLOAD(p0), k1 = KVLOAD(p1), k2 = KVLOAD(p2), k3 = KVLOAD(p3);
            float s0, s1, s2, s3;
            SCORE(k0, s0); SCORE(k1, s1); SCORE(k2, s2); SCORE(k3, s3);
            float mx = fmaxf(fmaxf(fmaxf(s0, s1), fmaxf(s2, s3)), m);
            float rs = __expf(m - mx);
            float p0e = __expf(s0 - mx), p1e = __expf(s1 - mx);
            float p2e = __expf(s2 - mx), p3e = __expf(s3 - mx);
            den = den * rs + ((p0e + p1e) + (p2e + p3e));
            acc.x = acc.x * rs + p0e*h2f(k0.z) + p1e*h2f(k1.z) + p2e*h2f(k2.z) + p3e*h2f(k3.z);
            acc.y = acc.y * rs + p0e*h2f(k0.w) + p1e*h2f(k1.w) + p2e*h2f(k2.w) + p3e*h2f(k3.w);
            m = mx;
        }
        for (; j < nc; ++j) {
            unsigned p0 = (unsigned)__shfl((int)pv, j);
            ushort4 k0 = KVLOAD(p0);
            float s0; SCORE(k0, s0);
            float mx = fmaxf(m, s0);
            float rs = __expf(m - mx);
            float pe = __expf(s0 - mx);
            den = den * rs + pe;
            acc.x = acc.x * rs + pe * h2f(k0.z);
            acc.y = acc.y * rs + pe * h2f(k0.w);
            m = mx;
        }
    }
#undef SCORE
#undef KVLOAD

    float inv = 1.f / (den + 1e-16f);
    float2 sk = *(const float2*)(qs + (size_t)i * 256 + 128 + 2*l);
    float2 o = { acc.x * inv + sk.x, acc.y * inv + sk.y };
    *(float2*)(out + (size_t)i * OUTW + 2*l) = o;
}

// ---------------- K8: BN column reduction ----------------
__global__ __launch_bounds__(256)
void bnreduce_kernel(const float* __restrict__ out, float* __restrict__ bnS,
                     float* __restrict__ bnQ, int N) {
    __shared__ float S[256], Q[256];
    const int tid = threadIdx.x;
    const int col = tid & 127, half = tid >> 7;
    float s = 0.f, q = 0.f;
    for (int r = blockIdx.x * 2 + half; r < N; r += gridDim.x * 2) {
        float v = out[(size_t)r * OUTW + col];
        s += v; q += v * v;
    }
    S[tid] = s; Q[tid] = q;
    __syncthreads();
    if (tid < 128) {
        atomicAdd(&bnS[tid], S[tid] + S[tid + 128]);
        atomicAdd(&bnQ[tid], Q[tid] + Q[tid + 128]);
    }
}

// ---------------- K9: BN stats -> per-column affine A,B ----------------
__global__ void bnstats_kernel(const float* __restrict__ bnS, const float* __restrict__ bnQ,
                               const float* __restrict__ gamma, const float* __restrict__ beta,
                               float* __restrict__ bnA, float* __restrict__ bnB, int N) {
    int c = threadIdx.x;
    if (c >= 128) return;
    float fN  = (float)N;
    float mu  = bnS[c] / fN;
    float var = bnQ[c] / fN - mu * mu;
    float rv  = rsqrtf(var + 1e-5f);
    float A   = rv * gamma[c];
    bnA[c] = A;
    bnB[c] = beta[c] - mu * A;
}

// ---------------- K10: BN apply + LeakyReLU (in-place) ----------------
__global__ void apply_kernel(float* __restrict__ out, const float* __restrict__ bnA,
                             const float* __restrict__ bnB, int total4) {
    int idx4 = blockIdx.x * blockDim.x + threadIdx.x;
    if (idx4 >= total4) return;
    float4 v = ((const float4*)out)[idx4];
    int c0 = (idx4 * 4) & 127;
    float y;
    y = bnA[c0    ] * v.x + bnB[c0    ]; v.x = (y > 0.f) ? y : 0.01f * y;
    y = bnA[c0 + 1] * v.y + bnB[c0 + 1]; v.y = (y > 0.f) ? y : 0.01f * y;
    y = bnA[c0 + 2] * v.z + bnB[c0 + 2]; v.z = (y > 0.f) ? y : 0.01f * y;
    y = bnA[c0 + 3] * v.w + bnB[c0 + 3]; v.w = (y > 0.f) ? y : 0.01f * y;
    ((float4*)out)[idx4] = v;
}

// ---------------- launch ----------------
static inline char* alignp(char* p) {
    return (char*)(((uintptr_t)p + 255) & ~(uintptr_t)255);
}

extern "C" void kernel_launch(void* const* d_in, const int* in_sizes, int n_in,
                              void* d_out, int out_size, void* d_ws, size_t ws_size,
                              hipStream_t stream) {
    const float* x     = (const float*)d_in[0];
    const int*   ei    = (const int*)  d_in[2];
    const int*   et    = (const int*)  d_in[3];
    const float* Wrel  = (const float*)d_in[4];
    const float* Wroot = (const float*)d_in[5];
    const float* brg   = (const float*)d_in[6];
    const float* Wq    = (const float*)d_in[7];
    const float* bq    = (const float*)d_in[8];
    const float* Wk    = (const float*)d_in[9];
    const float* bk    = (const float*)d_in[10];
    const float* Wv    = (const float*)d_in[11];
    const float* bv    = (const float*)d_in[12];
    const float* Wsk   = (const float*)d_in[13];
    const float* bsk   = (const float*)d_in[14];
    const float* gamma = (const float*)d_in[15];
    const float* beta  = (const float*)d_in[16];
    float* out = (float*)d_out;

    const int N = in_sizes[0] / G;
    const int E = in_sizes[3];
    const int NB_SCAN = (N + 1023) / 1024;

    // ---- workspace carve ----
    char* w = (char*)d_ws;
    int* deg   = (int*)w;            w += (size_t)N * 4;
    int* cntR  = (int*)w;            w += (size_t)RNUM * N * 4;
    float* bnS = (float*)w;          w += 128 * 4;
    float* bnQ = (float*)w;          w += 128 * 4;
    float* bnA = (float*)w;          w += 128 * 4;
    float* bnB = (float*)w;          w += 128 * 4;
    size_t zero_bytes = (size_t)(w - (char*)d_ws);
    w = alignp(w);
    int* bsum  = (int*)w;            w += 64 * 4;
    int* boff  = (int*)w;            w += 65 * 4;
    w = alignp(w);
    int* rowptr = (int*)w;           w += (size_t)(N + 1) * 4;
    w = alignp(w);
    int* cursor = (int*)w;           w += (size_t)N * 4;
    w = alignp(w);
    unsigned* epack = (unsigned*)w;  w += (size_t)E * 4;
    w = alignp(w);
    us* xh     = (us*)w;             w += (size_t)N * G * 2;
    w = alignp(w);
    float* xr  = (float*)w;          w += (size_t)N * OUTW * 4;
    w = alignp(w);
    // big aliased region: meanh [N][768] fp16; later qs [N][256] f32 + kvh [N][256] fp16
    us*    meanh = (us*)w;
    float* qs    = (float*)w;
    us*    kvh   = (us*)(w + (size_t)N * 256 * 4);

    hipMemsetAsync(d_ws, 0, zero_bytes, stream);

    int eb = (E + 255) / 256;
    count_kernel<<<eb, 256, 0, stream>>>(ei, et, deg, cntR, N, E);

    scan_part<<<NB_SCAN, 256, 0, stream>>>(deg, bsum, N);
    scan_top<<<1, 64, 0, stream>>>(bsum, boff, rowptr, NB_SCAN, N);
    scan_apply<<<NB_SCAN, 256, 0, stream>>>(deg, boff, rowptr, cursor, N);

    scatter_kernel<<<eb, 256, 0, stream>>>(ei, et, cursor, epack, N, E);

    int total8 = N * G / 8;
    xhalf_kernel<<<(total8 + 255) / 256, 256, 0, stream>>>(x, xh, total8);

    agg_kernel<<<(N + 3) / 4, 256, 0, stream>>>(xh, rowptr, epack, cntR, meanh, N);

    int gblocks = (N + 63) / 64;
    rgcn_gemm<<<gblocks, 256, 0, stream>>>(meanh, x, Wrel, Wroot, brg, xr, N);

    qkvs_kernel<<<gblocks, 256, 0, stream>>>(xr, Wq, bq, Wk, bk, Wv, bv, Wsk, bsk,
                                             qs, kvh, N);

    attn_kernel<<<(N + 3) / 4, 256, 0, stream>>>(qs, kvh, rowptr, epack, out, N);

    bnreduce_kernel<<<200, 256, 0, stream>>>(out, bnS, bnQ, N);
    bnstats_kernel<<<1, 128, 0, stream>>>(bnS, bnQ, gamma, beta, bnA, bnB, N);

    int total4 = N * OUTW / 4;
    apply_kernel<<<(total4 + 255) / 256, 256, 0, stream>>>(out, bnA, bnB, total4);
}

// Round 3
// 509.843 us; speedup vs baseline: 2.5597x; 1.9029x over previous
//
#include <hip/hip_runtime.h>
#include <hip/hip_fp16.h>
#include <stdint.h>

#define G      128
#define OUTW   128
#define RNUM   6

typedef unsigned short us;
typedef _Float16 f16x8 __attribute__((ext_vector_type(8)));
typedef float    f32x4 __attribute__((ext_vector_type(4)));

__device__ inline float h2f(us u) { __half h; *(us*)&h = u; return __half2float(h); }
__device__ inline us f2h(float f) { __half h = __float2half(f); return *(us*)&h; }

union FragU { f16x8 v; ushort4 u[2]; };

// ---------------- K1: degree + per-(relation,dst) counts ----------------
__global__ void count_kernel(const int* __restrict__ ei, const int* __restrict__ et,
                             int* __restrict__ deg, int* __restrict__ cntR,
                             int N, int E) {
    int e = blockIdx.x * blockDim.x + threadIdx.x;
    if (e >= E) return;
    int dst = ei[E + e];
    int r   = et[e];
    atomicAdd(&deg[dst], 1);
    atomicAdd(&cntR[r * N + dst], 1);
}

// ---------------- scan: 3-phase ----------------
__global__ __launch_bounds__(256)
void scan_part(const int* __restrict__ deg, int* __restrict__ bsum, int n) {
    __shared__ int s[256];
    int base = blockIdx.x * 1024, t = threadIdx.x;
    int v = 0;
    for (int j = 0; j < 4; ++j) { int idx = base + j * 256 + t; if (idx < n) v += deg[idx]; }
    s[t] = v; __syncthreads();
    for (int off = 128; off; off >>= 1) { if (t < off) s[t] += s[t + off]; __syncthreads(); }
    if (!t) bsum[blockIdx.x] = s[0];
}

__global__ void scan_top(const int* __restrict__ bsum, int* __restrict__ boff,
                         int* __restrict__ rowptr, int nb, int n) {
    int t = threadIdx.x;              // 64 threads, nb <= 64
    int v = (t < nb) ? bsum[t] : 0;
    for (int off = 1; off < 64; off <<= 1) {
        int y = __shfl_up(v, off);
        if (t >= off) v += y;
    }
    if (t < nb) boff[t + 1] = v;
    if (!t) boff[0] = 0;
    if (t == 63) rowptr[n] = v;       // grand total
}

__global__ __launch_bounds__(256)
void scan_apply(const int* __restrict__ deg, const int* __restrict__ boff,
                int* __restrict__ rowptr, int* __restrict__ cursor, int n) {
    __shared__ int L[1024];
    __shared__ int SS[256];
    int base = blockIdx.x * 1024, t = threadIdx.x;
    for (int j = 0; j < 4; ++j) { int idx = base + j * 256 + t; L[j * 256 + t] = (idx < n) ? deg[idx] : 0; }
    __syncthreads();
    int s0 = L[t*4] + L[t*4+1] + L[t*4+2] + L[t*4+3];
    SS[t] = s0; __syncthreads();
    for (int off = 1; off < 256; off <<= 1) {
        int y = (t >= off) ? SS[t - off] : 0;
        __syncthreads();
        SS[t] += y;
        __syncthreads();
    }
    int e0 = (t ? SS[t - 1] : 0) + boff[blockIdx.x];
    int4 ov;
    int a;
    a = L[t*4+0]; ov.x = e0; e0 += a;
    a = L[t*4+1]; ov.y = e0; e0 += a;
    a = L[t*4+2]; ov.z = e0; e0 += a;
    a = L[t*4+3]; ov.w = e0; e0 += a;
    int idx0 = base + t * 4;
    if (idx0 + 3 < n) {
        *(int4*)(rowptr + idx0) = ov;
        *(int4*)(cursor + idx0) = ov;
    } else {
        int vals[4] = {ov.x, ov.y, ov.z, ov.w};
        for (int k = 0; k < 4; ++k)
            if (idx0 + k < n) { rowptr[idx0 + k] = vals[k]; cursor[idx0 + k] = vals[k]; }
    }
}

// ---------------- K3: scatter edges into CSR (src | rel<<16 packed) ----------------
__global__ void scatter_kernel(const int* __restrict__ ei, const int* __restrict__ et,
                               int* __restrict__ cursor, unsigned int* __restrict__ epack,
                               int N, int E) {
    int e = blockIdx.x * blockDim.x + threadIdx.x;
    if (e >= E) return;
    int src = ei[e];
    int dst = ei[E + e];
    int r   = et[e];
    int pos = atomicAdd(&cursor[dst], 1);
    epack[pos] = (unsigned int)src | ((unsigned int)r << 16);
}

// ---------------- K: fp32 -> fp16 copy of x ----------------
__global__ void xhalf_kernel(const float* __restrict__ x, us* __restrict__ xh, int total8) {
    int i = blockIdx.x * blockDim.x + threadIdx.x;
    if (i >= total8) return;
    float4 a = ((const float4*)x)[2*i];
    float4 b = ((const float4*)x)[2*i+1];
    ushort4 u0 = { f2h(a.x), f2h(a.y), f2h(a.z), f2h(a.w) };
    ushort4 u1 = { f2h(b.x), f2h(b.y), f2h(b.z), f2h(b.w) };
    ((ushort4*)xh)[2*i]   = u0;
    ((ushort4*)xh)[2*i+1] = u1;
}

// ---------------- weight prep: fp16 fragment-layout conversions ----------------
// Btr[kq][n][i] = Wcat[4kq+i][n], Wcat = [Wrel(768) ; Wroot(128)], kq<224, n<128
__global__ __launch_bounds__(256)
void wconv_rgcn(const float* __restrict__ Wrel, const float* __restrict__ Wroot,
                ushort4* __restrict__ Btr) {
    int idx = blockIdx.x * 256 + threadIdx.x;
    if (idx >= 224 * 128) return;
    int kq = idx >> 7, n = idx & 127;
    ushort4 o;
    us* op = (us*)&o;
#pragma unroll
    for (int i = 0; i < 4; ++i) {
        int k = 4 * kq + i;
        float v = (k < 768) ? Wrel[(size_t)k * 128 + n] : Wroot[(size_t)(k - 768) * 128 + n];
        op[i] = f2h(v);
    }
    Btr[idx] = o;
}

// Btq[kq][n][i] = Wsel(n/128)[4kq+i][n%128], kq<32, n<512 (q|k|v|s)
__global__ __launch_bounds__(256)
void wconv_qkvs(const float* __restrict__ Wq, const float* __restrict__ Wk,
                const float* __restrict__ Wv, const float* __restrict__ Ws,
                ushort4* __restrict__ Btq) {
    int idx = blockIdx.x * 256 + threadIdx.x;
    if (idx >= 32 * 512) return;
    int kq = idx >> 9, n = idx & 511;
    int quad = n >> 7, nl = n & 127;
    const float* W = (quad == 0) ? Wq : (quad == 1) ? Wk : (quad == 2) ? Wv : Ws;
    ushort4 o;
    us* op = (us*)&o;
#pragma unroll
    for (int i = 0; i < 4; ++i) {
        int k = 4 * kq + i;
        op[i] = f2h(W[(size_t)k * 128 + nl]);
    }
    Btq[idx] = o;
}

// ---------------- K4: aggregation (wave per node, no LDS, fp16 gather) ----------------
__global__ __launch_bounds__(256)
void agg_kernel(const us* __restrict__ xh, const int* __restrict__ rowptr,
                const unsigned* __restrict__ epack, const int* __restrict__ cntR,
                us* __restrict__ meanh, int N) {
    const int wv = threadIdx.x >> 6, l = threadIdx.x & 63;
    const int i = blockIdx.x * 4 + wv;
    if (i >= N) return;
    const int e0 = rowptr[i], e1 = rowptr[i + 1];
    float2 a0{0,0}, a1{0,0}, a2{0,0}, a3{0,0}, a4{0,0}, a5{0,0};

#define LOADX(P) (*(const ushort2*)(xh + (size_t)((P) & 0xFFFFu) * G + 2*l))
#define ACC(P, U) { unsigned r_ = (P) >> 16; float vx_ = h2f((U).x), vy_ = h2f((U).y); \
    if      (r_ == 0) { a0.x += vx_; a0.y += vy_; } \
    else if (r_ == 1) { a1.x += vx_; a1.y += vy_; } \
    else if (r_ == 2) { a2.x += vx_; a2.y += vy_; } \
    else if (r_ == 3) { a3.x += vx_; a3.y += vy_; } \
    else if (r_ == 4) { a4.x += vx_; a4.y += vy_; } \
    else              { a5.x += vx_; a5.y += vy_; } }

    for (int base = e0; base < e1; base += 64) {
        const int nc = min(64, e1 - base);
        unsigned pv = 0;
        if (base + l < e1) pv = epack[base + l];
        int j = 0;
        for (; j + 8 <= nc; j += 8) {
            unsigned q0 = (unsigned)__shfl((int)pv, j+0);
            unsigned q1 = (unsigned)__shfl((int)pv, j+1);
            unsigned q2 = (unsigned)__shfl((int)pv, j+2);
            unsigned q3 = (unsigned)__shfl((int)pv, j+3);
            unsigned q4 = (unsigned)__shfl((int)pv, j+4);
            unsigned q5 = (unsigned)__shfl((int)pv, j+5);
            unsigned q6 = (unsigned)__shfl((int)pv, j+6);
            unsigned q7 = (unsigned)__shfl((int)pv, j+7);
            ushort2 u0 = LOADX(q0), u1 = LOADX(q1), u2 = LOADX(q2), u3 = LOADX(q3);
            ushort2 u4 = LOADX(q4), u5 = LOADX(q5), u6 = LOADX(q6), u7 = LOADX(q7);
            ACC(q0,u0); ACC(q1,u1); ACC(q2,u2); ACC(q3,u3);
            ACC(q4,u4); ACC(q5,u5); ACC(q6,u6); ACC(q7,u7);
        }
        for (; j < nc; ++j) {
            unsigned q0 = (unsigned)__shfl((int)pv, j);
            ushort2 u0 = LOADX(q0);
            ACC(q0,u0);
        }
    }
#undef ACC
#undef LOADX

    us* mrow = meanh + (size_t)i * 768 + 2*l;
#define WR(RIDX, A) { \
    float c_ = (float)cntR[(RIDX) * N + i]; \
    float s_ = 1.f / fmaxf(c_, 1.f); \
    ushort2 t_ = { f2h((A).x * s_), f2h((A).y * s_) }; \
    *(ushort2*)(mrow + (RIDX) * G) = t_; }
    WR(0, a0); WR(1, a1); WR(2, a2); WR(3, a3); WR(4, a4); WR(5, a5);
#undef WR
}

// ---------------- K5: RGCN GEMM via MFMA  xrh = [means | x] @ [Wrel;Wroot] + b ----------------
// 64 rows/block, 4 waves x (16 rows x 128 cols). K = 896 in 14 chunks of 64.
__global__ __launch_bounds__(256)
void rgcn_mfma(const us* __restrict__ meanh, const us* __restrict__ xh,
               const ushort4* __restrict__ Btr, const float* __restrict__ brg,
               us* __restrict__ xrh, int N) {
    __shared__ ushort4 Ald[16 * 64];     // [kq][row] : At[kq][m][0..3] fp16, 8 KB
    const int tid = threadIdx.x;
    const int w = tid >> 6, l = tid & 63;
    const int lh = l >> 4, lm = l & 15;
    const int base = blockIdx.x * 64;
    const int arow = w * 16 + lm;        // A-frag row within block tile

    f32x4 acc[8];
#pragma unroll
    for (int ct = 0; ct < 8; ++ct) {
        float b = brg[ct * 16 + lm];
        acc[ct] = (f32x4){b, b, b, b};
    }

    const int srow = tid >> 2;           // staging: row within tile
    const int sk0  = (tid & 3) * 16;     // staging: first k of 16

    for (int ch = 0; ch < 14; ++ch) {
        int gi = base + srow;
        int4 d0 = {0,0,0,0}, d1 = {0,0,0,0};
        if (gi < N) {
            const us* src = (ch < 12) ? (meanh + (size_t)gi * 768 + ch * 64 + sk0)
                                      : (xh    + (size_t)gi * 128 + (ch - 12) * 64 + sk0);
            d0 = *(const int4*)src;
            d1 = *(const int4*)(src + 8);
        }
        __syncthreads();                 // previous chunk's reads done
        int kqb = sk0 >> 2;
        Ald[(kqb + 0) * 64 + srow] = ((ushort4*)&d0)[0];
        Ald[(kqb + 1) * 64 + srow] = ((ushort4*)&d0)[1];
        Ald[(kqb + 2) * 64 + srow] = ((ushort4*)&d1)[0];
        Ald[(kqb + 3) * 64 + srow] = ((ushort4*)&d1)[1];
        __syncthreads();

#pragma unroll
        for (int s = 0; s < 2; ++s) {
            FragU af;
            int kql = s * 8 + lh;
            af.u[0] = Ald[kql * 64 + arow];
            af.u[1] = Ald[(kql + 4) * 64 + arow];
            int kqg = ch * 16 + s * 8 + lh;
            const ushort4* B0 = Btr + (size_t)kqg * 128;
            const ushort4* B1 = Btr + (size_t)(kqg + 4) * 128;
#pragma unroll
            for (int ct = 0; ct < 8; ++ct) {
                FragU bf;
                bf.u[0] = B0[ct * 16 + lm];
                bf.u[1] = B1[ct * 16 + lm];
                acc[ct] = __builtin_amdgcn_mfma_f32_16x16x32_f16(af.v, bf.v, acc[ct], 0, 0, 0);
            }
        }
    }

    // store: D row = 4*lh + i, col = ct*16 + lm
#pragma unroll
    for (int ct = 0; ct < 8; ++ct) {
#pragma unroll
        for (int i = 0; i < 4; ++i) {
            int r = base + w * 16 + 4 * lh + i;
            if (r < N) xrh[(size_t)r * 128 + ct * 16 + lm] = f2h(acc[ct][i]);
        }
    }
}

// ---------------- K6: q|k|v|skip via MFMA ----------------
// 16 rows/block; wave w computes quadrant w (q,k,v,skip). K = 128 in 4 steps.
__global__ __launch_bounds__(256)
void qkvs_mfma(const us* __restrict__ xrh, const ushort4* __restrict__ Btq,
               const float* __restrict__ bq, const float* __restrict__ bk,
               const float* __restrict__ bv, const float* __restrict__ bs,
               float* __restrict__ qs, us* __restrict__ kvh, int N) {
    __shared__ ushort4 Ald[32 * 16];     // [kq][m], 4 KB
    const int tid = threadIdx.x;
    const int w = tid >> 6, l = tid & 63;
    const int lh = l >> 4, lm = l & 15;
    const int base = blockIdx.x * 16;

    {   // stage 16 rows x 128 k : 1 int4 per thread
        int row = tid >> 4, k0 = (tid & 15) * 8;
        int gi = base + row;
        int4 d0 = {0,0,0,0};
        if (gi < N) d0 = *(const int4*)(xrh + (size_t)gi * 128 + k0);
        int kqb = k0 >> 2;
        Ald[(kqb + 0) * 16 + row] = ((ushort4*)&d0)[0];
        Ald[(kqb + 1) * 16 + row] = ((ushort4*)&d0)[1];
    }
    __syncthreads();

    const float* bias = (w == 0) ? bq : (w == 1) ? bk : (w == 2) ? bv : bs;
    f32x4 acc[8];
#pragma unroll
    for (int ct = 0; ct < 8; ++ct) {
        float b = bias[ct * 16 + lm];
        acc[ct] = (f32x4){b, b, b, b};
    }

#pragma unroll
    for (int s = 0; s < 4; ++s) {
        FragU af;
        int kq = s * 8 + lh;
        af.u[0] = Ald[kq * 16 + lm];
        af.u[1] = Ald[(kq + 4) * 16 + lm];
        const ushort4* B0 = Btq + (size_t)kq * 512 + w * 128;
        const ushort4* B1 = Btq + (size_t)(kq + 4) * 512 + w * 128;
#pragma unroll
        for (int ct = 0; ct < 8; ++ct) {
            FragU bf;
            bf.u[0] = B0[ct * 16 + lm];
            bf.u[1] = B1[ct * 16 + lm];
            acc[ct] = __builtin_amdgcn_mfma_f32_16x16x32_f16(af.v, bf.v, acc[ct], 0, 0, 0);
        }
    }

    if (w == 0 || w == 3) {
        int off = (w == 0) ? 0 : 128;
#pragma unroll
        for (int ct = 0; ct < 8; ++ct)
#pragma unroll
            for (int i = 0; i < 4; ++i) {
                int r = base + 4 * lh + i;
                if (r < N) qs[(size_t)r * 256 + off + ct * 16 + lm] = acc[ct][i];
            }
    } else {
        int off = (w == 1) ? 0 : 2;      // k or v interleave slot
#pragma unroll
        for (int ct = 0; ct < 8; ++ct)
#pragma unroll
            for (int i = 0; i < 4; ++i) {
                int r = base + 4 * lh + i;
                int col = ct * 16 + lm;
                if (r < N) kvh[(size_t)r * 256 + (col >> 1) * 4 + (col & 1) + off] = f2h(acc[ct][i]);
            }
    }
}

// ---------------- K7: attention (wave per node, 4-edge batched online softmax) ----------------
__global__ __launch_bounds__(256)
void attn_kernel(const float* __restrict__ qs, const us* __restrict__ kvh,
                 const int* __restrict__ rowptr, const unsigned* __restrict__ epack,
                 float* __restrict__ out, int N) {
    const int wv = threadIdx.x >> 6, l = threadIdx.x & 63;
    const int i = blockIdx.x * 4 + wv;
    if (i >= N) return;
    const float QS = 0.17677669529663687f;   // 1/sqrt(32)

    float2 q2 = *(const float2*)(qs + (size_t)i * 256 + 2*l);
    q2.x *= QS; q2.y *= QS;

    float m = -INFINITY, den = 0.f;
    float2 acc = {0.f, 0.f};
    const int e0 = rowptr[i], e1 = rowptr[i + 1];

#define KVLOAD(P) (*(const ushort4*)(kvh + (size_t)((P) & 0xFFFFu) * 256 + 4*l))
#define SCORE(U, S) { \
    float s_ = q2.x * h2f((U).x) + q2.y * h2f((U).y); \
    s_ += __shfl_xor(s_, 1, 16); s_ += __shfl_xor(s_, 2, 16); \
    s_ += __shfl_xor(s_, 4, 16); s_ += __shfl_xor(s_, 8, 16); \
    S = s_; }

    for (int base = e0; base < e1; base += 64) {
        const int nc = min(64, e1 - base);
        unsigned pv = 0;
        if (base + l < e1) pv = epack[base + l];
        int j = 0;
        for (; j + 4 <= nc; j += 4) {
            unsigned p0 = (unsigned)__shfl((int)pv, j+0);
            unsigned p1 = (unsigned)__shfl((int)pv, j+1);
            unsigned p2 = (unsigned)__shfl((int)pv, j+2);
            unsigned p3 = (unsigned)__shfl((int)pv, j+3);
            ushort4 k0 = KVLOAD(p0), k1 = KVLOAD(p1), k2 = KVLOAD(p2), k3 = KVLOAD(p3);
            float s0, s1, s2, s3;
            SCORE(k0, s0); SCORE(k1, s1); SCORE(k2, s2); SCORE(k3, s3);
            float mx = fmaxf(fmaxf(fmaxf(s0, s1), fmaxf(s2, s3)), m);
            float rs = __expf(m - mx);
            float p0e = __expf(s0 - mx), p1e = __expf(s1 - mx);
            float p2e = __expf(s2 - mx), p3e = __expf(s3 - mx);
            den = den * rs + ((p0e + p1e) + (p2e + p3e));
            acc.x = acc.x * rs + p0e*h2f(k0.z) + p1e*h2f(k1.z) + p2e*h2f(k2.z) + p3e*h2f(k3.z);
            acc.y = acc.y * rs + p0e*h2f(k0.w) + p1e*h2f(k1.w) + p2e*h2f(k2.w) + p3e*h2f(k3.w);
            m = mx;
        }
        for (; j < nc; ++j) {
            unsigned p0 = (unsigned)__shfl((int)pv, j);
            ushort4 k0 = KVLOAD(p0);
            float s0; SCORE(k0, s0);
            float mx = fmaxf(m, s0);
            float rs = __expf(m - mx);
            float pe = __expf(s0 - mx);
            den = den * rs + pe;
            acc.x = acc.x * rs + pe * h2f(k0.z);
            acc.y = acc.y * rs + pe * h2f(k0.w);
            m = mx;
        }
    }
#undef SCORE
#undef KVLOAD

    float inv = 1.f / (den + 1e-16f);
    float2 sk = *(const float2*)(qs + (size_t)i * 256 + 128 + 2*l);
    float2 o = { acc.x * inv + sk.x, acc.y * inv + sk.y };
    *(float2*)(out + (size_t)i * OUTW + 2*l) = o;
}

// ---------------- K8: BN column reduction ----------------
__global__ __launch_bounds__(256)
void bnreduce_kernel(const float* __restrict__ out, float* __restrict__ bnS,
                     float* __restrict__ bnQ, int N) {
    __shared__ float S[256], Q[256];
    const int tid = threadIdx.x;
    const int col = tid & 127, half = tid >> 7;
    float s = 0.f, q = 0.f;
    for (int r = blockIdx.x * 2 + half; r < N; r += gridDim.x * 2) {
        float v = out[(size_t)r * OUTW + col];
        s += v; q += v * v;
    }
    S[tid] = s; Q[tid] = q;
    __syncthreads();
    if (tid < 128) {
        atomicAdd(&bnS[tid], S[tid] + S[tid + 128]);
        atomicAdd(&bnQ[tid], Q[tid] + Q[tid + 128]);
    }
}

// ---------------- K9: BN stats -> per-column affine A,B ----------------
__global__ void bnstats_kernel(const float* __restrict__ bnS, const float* __restrict__ bnQ,
                               const float* __restrict__ gamma, const float* __restrict__ beta,
                               float* __restrict__ bnA, float* __restrict__ bnB, int N) {
    int c = threadIdx.x;
    if (c >= 128) return;
    float fN  = (float)N;
    float mu  = bnS[c] / fN;
    float var = bnQ[c] / fN - mu * mu;
    float rv  = rsqrtf(var + 1e-5f);
    float A   = rv * gamma[c];
    bnA[c] = A;
    bnB[c] = beta[c] - mu * A;
}

// ---------------- K10: BN apply + LeakyReLU (in-place) ----------------
__global__ void apply_kernel(float* __restrict__ out, const float* __restrict__ bnA,
                             const float* __restrict__ bnB, int total4) {
    int idx4 = blockIdx.x * blockDim.x + threadIdx.x;
    if (idx4 >= total4) return;
    float4 v = ((const float4*)out)[idx4];
    int c0 = (idx4 * 4) & 127;
    float y;
    y = bnA[c0    ] * v.x + bnB[c0    ]; v.x = (y > 0.f) ? y : 0.01f * y;
    y = bnA[c0 + 1] * v.y + bnB[c0 + 1]; v.y = (y > 0.f) ? y : 0.01f * y;
    y = bnA[c0 + 2] * v.z + bnB[c0 + 2]; v.z = (y > 0.f) ? y : 0.01f * y;
    y = bnA[c0 + 3] * v.w + bnB[c0 + 3]; v.w = (y > 0.f) ? y : 0.01f * y;
    ((float4*)out)[idx4] = v;
}

// ---------------- launch ----------------
static inline char* alignp(char* p) {
    return (char*)(((uintptr_t)p + 255) & ~(uintptr_t)255);
}

extern "C" void kernel_launch(void* const* d_in, const int* in_sizes, int n_in,
                              void* d_out, int out_size, void* d_ws, size_t ws_size,
                              hipStream_t stream) {
    const float* x     = (const float*)d_in[0];
    const int*   ei    = (const int*)  d_in[2];
    const int*   et    = (const int*)  d_in[3];
    const float* Wrel  = (const float*)d_in[4];
    const float* Wroot = (const float*)d_in[5];
    const float* brg   = (const float*)d_in[6];
    const float* Wq    = (const float*)d_in[7];
    const float* bq    = (const float*)d_in[8];
    const float* Wk    = (const float*)d_in[9];
    const float* bk    = (const float*)d_in[10];
    const float* Wv    = (const float*)d_in[11];
    const float* bv    = (const float*)d_in[12];
    const float* Wsk   = (const float*)d_in[13];
    const float* bsk   = (const float*)d_in[14];
    const float* gamma = (const float*)d_in[15];
    const float* beta  = (const float*)d_in[16];
    float* out = (float*)d_out;

    const int N = in_sizes[0] / G;
    const int E = in_sizes[3];
    const int NB_SCAN = (N + 1023) / 1024;

    // ---- workspace carve ----
    char* w = (char*)d_ws;
    int* deg   = (int*)w;            w += (size_t)N * 4;
    int* cntR  = (int*)w;            w += (size_t)RNUM * N * 4;
    float* bnS = (float*)w;          w += 128 * 4;
    float* bnQ = (float*)w;          w += 128 * 4;
    float* bnA = (float*)w;          w += 128 * 4;
    float* bnB = (float*)w;          w += 128 * 4;
    size_t zero_bytes = (size_t)(w - (char*)d_ws);
    w = alignp(w);
    int* bsum  = (int*)w;            w += 64 * 4;
    int* boff  = (int*)w;            w += 65 * 4;
    w = alignp(w);
    int* rowptr = (int*)w;           w += (size_t)(N + 1) * 4;
    w = alignp(w);
    int* cursor = (int*)w;           w += (size_t)N * 4;
    w = alignp(w);
    unsigned* epack = (unsigned*)w;  w += (size_t)E * 4;
    w = alignp(w);
    us* xh     = (us*)w;             w += (size_t)N * G * 2;
    w = alignp(w);
    us* xrh    = (us*)w;             w += (size_t)N * OUTW * 2;
    w = alignp(w);
    ushort4* Btr = (ushort4*)w;      w += (size_t)224 * 128 * 8;
    w = alignp(w);
    ushort4* Btq = (ushort4*)w;      w += (size_t)32 * 512 * 8;
    w = alignp(w);
    // big aliased region: meanh [N][768] fp16; later qs [N][256] f32 + kvh [N][256] fp16
    us*    meanh = (us*)w;
    float* qs    = (float*)w;
    us*    kvh   = (us*)(w + (size_t)N * 256 * 4);

    hipMemsetAsync(d_ws, 0, zero_bytes, stream);

    int eb = (E + 255) / 256;
    count_kernel<<<eb, 256, 0, stream>>>(ei, et, deg, cntR, N, E);

    scan_part<<<NB_SCAN, 256, 0, stream>>>(deg, bsum, N);
    scan_top<<<1, 64, 0, stream>>>(bsum, boff, rowptr, NB_SCAN, N);
    scan_apply<<<NB_SCAN, 256, 0, stream>>>(deg, boff, rowptr, cursor, N);

    scatter_kernel<<<eb, 256, 0, stream>>>(ei, et, cursor, epack, N, E);

    int total8 = N * G / 8;
    xhalf_kernel<<<(total8 + 255) / 256, 256, 0, stream>>>(x, xh, total8);

    wconv_rgcn<<<112, 256, 0, stream>>>(Wrel, Wroot, Btr);
    wconv_qkvs<<<64, 256, 0, stream>>>(Wq, Wk, Wv, Wsk, Btq);

    agg_kernel<<<(N + 3) / 4, 256, 0, stream>>>(xh, rowptr, epack, cntR, meanh, N);

    rgcn_mfma<<<(N + 63) / 64, 256, 0, stream>>>(meanh, xh, Btr, brg, xrh, N);

    qkvs_mfma<<<(N + 15) / 16, 256, 0, stream>>>(xrh, Btq, bq, bk, bv, bsk, qs, kvh, N);

    attn_kernel<<<(N + 3) / 4, 256, 0, stream>>>(qs, kvh, rowptr, epack, out, N);

    bnreduce_kernel<<<200, 256, 0, stream>>>(out, bnS, bnQ, N);
    bnstats_kernel<<<1, 128, 0, stream>>>(bnS, bnQ, gamma, beta, bnA, bnB, N);

    int total4 = N * OUTW / 4;
    apply_kernel<<<(total4 + 255) / 256, 256, 0, stream>>>(out, bnA, bnB, total4);
}